// Round 8
// baseline (162.214 us; speedup 1.0000x reference)
//
#include <hip/hip_runtime.h>
#include <hip/hip_bf16.h>

#define N_NODES 100000
#define N_EDGES 1600000
#define IN_FEAT 64
#define OUT_FEAT 64
#define NUM_RELS 8

#define BSHIFT 7
#define BSZ 128                                   // nodes per bucket
#define NB ((N_NODES + BSZ - 1) / BSZ)            // 782 buckets
#define CHUNK 4096
#define NCHUNK ((N_EDGES + CHUNK - 1) / CHUNK)    // 391 edge chunks
#define PSTR 392                                  // poff row stride
#define MAXBUCK 2944                              // bucket LDS cap (mean 2046, ~20 sigma)

typedef __attribute__((ext_vector_type(8))) short short8;
typedef __attribute__((ext_vector_type(8))) unsigned short ushort8;
typedef __attribute__((ext_vector_type(4))) float f32x4;

// bf16 helpers
static __device__ __forceinline__ unsigned short f2bf(float x) {
    unsigned u = __float_as_uint(x);
    unsigned r = (u + 0x7FFFu + ((u >> 16) & 1u)) >> 16;
    return (unsigned short)r;
}
static __device__ __forceinline__ float bf2f(unsigned short h) {
    return __uint_as_float(((unsigned)h) << 16);
}
static __device__ __forceinline__ float bflo(unsigned v) { return __uint_as_float(v << 16); }
static __device__ __forceinline__ float bfhi(unsigned v) { return __uint_as_float(v & 0xFFFF0000u); }

// ---------------------------------------------------------------------------
// K0a: one-time W transpose+cast: Wt[r][o][i] (bf16) = W[r][i][o]. 64KB,
// L2-resident for all of k_agg's B-fragment loads.
// ---------------------------------------------------------------------------
__global__ __launch_bounds__(256) void k_prep(const float* __restrict__ W,
                                              unsigned short* __restrict__ Wt) {
    __shared__ float Wl[64 * 64];   // [i][o]
    const int r = blockIdx.x, t = threadIdx.x;
    #pragma unroll
    for (int it = 0; it < 16; ++it) {
        int idx = it * 256 + t;
        Wl[idx] = W[(size_t)r * 4096 + idx];
    }
    __syncthreads();
    const int o = t >> 2, iq = t & 3;           // 16 i-values per thread
    unsigned short tmp[16];
    #pragma unroll
    for (int k = 0; k < 16; ++k) tmp[k] = f2bf(Wl[(iq * 16 + k) * 64 + o]);
    ushort8* dst = (ushort8*)(Wt + ((size_t)r * 64 + o) * 64 + iq * 16);
    dst[0] = *(ushort8*)&tmp[0];
    dst[1] = *(ushort8*)&tmp[8];
}

// ---------------------------------------------------------------------------
// K0b: featb[n][i] (bf16) = feat[n][i]. 12.8MB -> the gather working set
// becomes L2/L3-resident (vs the old 102MB tr intermediate fetched from HBM).
// ---------------------------------------------------------------------------
__global__ __launch_bounds__(256) void k_featb(const float* __restrict__ feat,
                                               unsigned short* __restrict__ featb) {
    int i = blockIdx.x * 256 + threadIdx.x;    // one ushort8 (8 elems) per thread
    if (i >= N_NODES * 8) return;
    float4 v0 = ((const float4*)feat)[(size_t)i * 2];
    float4 v1 = ((const float4*)feat)[(size_t)i * 2 + 1];
    ushort8 pw;
    pw[0] = f2bf(v0.x); pw[1] = f2bf(v0.y); pw[2] = f2bf(v0.z); pw[3] = f2bf(v0.w);
    pw[4] = f2bf(v1.x); pw[5] = f2bf(v1.y); pw[6] = f2bf(v1.z); pw[7] = f2bf(v1.w);
    ((ushort8*)featb)[i] = pw;
}

// ---------------------------------------------------------------------------
// Exclusive block scan over arr[0..1023] (LDS), 256 threads. Returns total.
// ---------------------------------------------------------------------------
__device__ __forceinline__ int block_scan1024(int* arr, int* tmp) {
    const int t = threadIdx.x;
    const int i0 = t * 4;
    int v0 = arr[i0], v1 = arr[i0 + 1], v2 = arr[i0 + 2], v3 = arr[i0 + 3];
    int s = v0 + v1 + v2 + v3;
    tmp[t] = s;
    __syncthreads();
    for (int off = 1; off < 256; off <<= 1) {
        int x = (t >= off) ? tmp[t - off] : 0;
        __syncthreads();
        tmp[t] += x;
        __syncthreads();
    }
    int excl = tmp[t] - s;
    int total = tmp[255];
    arr[i0]     = excl;
    arr[i0 + 1] = excl + v0;
    arr[i0 + 2] = excl + v0 + v1;
    arr[i0 + 3] = excl + v0 + v1 + v2;
    __syncthreads();
    return total;
}

// ---------------------------------------------------------------------------
// S1: per-chunk bucket histogram. cnt_kb[k][b] (coalesced writes).
// ---------------------------------------------------------------------------
__global__ __launch_bounds__(256) void k_bhist(const int* __restrict__ dst,
                                               int* __restrict__ cnt_kb) {
    __shared__ int h[NB];
    const int k = blockIdx.x, t = threadIdx.x;
    for (int i = t; i < NB; i += 256) h[i] = 0;
    __syncthreads();
    const int e0 = k * CHUNK;
    #pragma unroll
    for (int i = 0; i < 16; ++i) {
        int e = e0 + t + i * 256;
        if (e < N_EDGES) atomicAdd(&h[dst[e] >> BSHIFT], 1);
    }
    __syncthreads();
    for (int i = t; i < NB; i += 256) cnt_kb[(size_t)k * NB + i] = h[i];
}

// ---------------------------------------------------------------------------
// S2a: per-bucket prefix over chunks: poff[b][k]; bucket totals -> btot.
// ---------------------------------------------------------------------------
__global__ __launch_bounds__(256) void k_scan_bucket(const int* __restrict__ cnt_kb,
                                                     int* __restrict__ poff,
                                                     int* __restrict__ btot) {
    __shared__ int arr[1024];
    __shared__ int tmp[256];
    const int b = blockIdx.x, t = threadIdx.x;
    for (int i = t; i < 1024; i += 256)
        arr[i] = (i < NCHUNK) ? cnt_kb[(size_t)i * NB + b] : 0;
    __syncthreads();
    int total = block_scan1024(arr, tmp);
    for (int i = t; i < NCHUNK; i += 256) poff[(size_t)b * PSTR + i] = arr[i];
    if (t == 0) btot[b] = total;
}

// ---------------------------------------------------------------------------
// S2b: scan bucket totals -> bbase[0..NB], bbase[NB]=E.
// ---------------------------------------------------------------------------
__global__ __launch_bounds__(256) void k_scan_tot(const int* __restrict__ btot,
                                                  int* __restrict__ bbase) {
    __shared__ int arr[1024];
    __shared__ int tmp[256];
    const int t = threadIdx.x;
    for (int i = t; i < 1024; i += 256) arr[i] = (i < NB) ? btot[i] : 0;
    __syncthreads();
    block_scan1024(arr, tmp);
    for (int i = t; i < NB; i += 256) bbase[i] = arr[i];
    if (t == 0) bbase[NB] = N_EDGES;
}

// ---------------------------------------------------------------------------
// S3: bin edges into bucket-sorted payload with EXACT positions (line-dense
// writes). payload.x = src | ldst<<17 | rel<<24  (src<2^17, ldst 7b, rel 3b)
// -> (x>>17)&1023 is the in-bucket sort key rel*128+ldst.  payload.y = norm.
// ---------------------------------------------------------------------------
__global__ __launch_bounds__(256) void k_bin(const int* __restrict__ etypes,
                                             const int* __restrict__ src,
                                             const int* __restrict__ dst,
                                             const float* __restrict__ norm,
                                             const int* __restrict__ poff,
                                             const int* __restrict__ bbase,
                                             int2* __restrict__ payload) {
    __shared__ int hist[1024];
    __shared__ int tmp[256];
    __shared__ int lcur[NB];
    __shared__ int goff[NB];
    __shared__ int2 ordered[CHUNK];
    __shared__ unsigned short bkt_of[CHUNK];
    const int k = blockIdx.x, t = threadIdx.x;
    const int e0 = k * CHUNK;
    const int cnt = min(CHUNK, N_EDGES - e0);

    for (int i = t; i < 1024; i += 256) hist[i] = 0;
    __syncthreads();
    #pragma unroll
    for (int i = 0; i < 16; ++i) {
        int e = e0 + t + i * 256;
        if (e < N_EDGES) atomicAdd(&hist[dst[e] >> BSHIFT], 1);
    }
    __syncthreads();
    block_scan1024(hist, tmp);           // hist -> local exclusive base
    for (int i = t; i < NB; i += 256) {
        int lb = hist[i];
        lcur[i] = lb;
        goff[i] = bbase[i] + poff[(size_t)i * PSTR + k] - lb;
    }
    __syncthreads();
    #pragma unroll
    for (int i = 0; i < 16; ++i) {
        int e = e0 + t + i * 256;
        if (e < N_EDGES) {
            int d = dst[e];
            int b = d >> BSHIFT;
            int pos = atomicAdd(&lcur[b], 1);
            int pack = src[e] | ((d & (BSZ - 1)) << 17) | (etypes[e] << 24);
            ordered[pos] = make_int2(pack, __float_as_int(norm[e]));
            bkt_of[pos] = (unsigned short)b;
        }
    }
    __syncthreads();
    for (int j = t; j < cnt; j += 256) {
        int b = bkt_of[j];
        payload[goff[b] + j] = ordered[j];   // consecutive j -> consecutive g within a run
    }
}

// ---------------------------------------------------------------------------
// S4 (fused): block (512 thr) per bucket. out[d] = sum_r P_r[d] @ W[r] where
// P_r[d] = sum_{e in (d,r)} norm*featb[src]. Counting-sort bucket edges by
// key=(rel,node) (1024 bins); then 8 rel passes: register gather-accumulate
// of P (64 groups x 8 lanes, 2 nodes each — round-6's proven atomic-free
// structure, now reading the 12.8MB L2/L3-resident featb), P->LDS bf16,
// 8 waves MFMA P@Wt[r] accumulating persistent C frags (round-7-verified
// fragment indexing). One f32 row store per node after 8 rels.
// LDS: P region unioned with sort scratch (cnt/ncur/stmp) -> 50.8KB total.
// ---------------------------------------------------------------------------
__global__ __launch_bounds__(512, 6) void k_agg(const unsigned short* __restrict__ featb,
                                                const unsigned short* __restrict__ Wt,
                                                const float* __restrict__ Worig,
                                                const float* __restrict__ featf,
                                                const int2* __restrict__ payload,
                                                const int* __restrict__ bbase,
                                                float* __restrict__ out) {
    __shared__ int2 pseg[MAXBUCK];              // 23,552 B
    __shared__ unsigned short sidx[MAXBUCK];    //  5,888 B
    __shared__ int nbase[1025];                 //  4,100 B
    __shared__ __align__(16) unsigned char uu[128 * 72 * 2];   // 18,432 B union
    unsigned short* P = (unsigned short*)uu;    // [128][72] bf16 (rel-pass phase)
    int* cnt  = (int*)uu;                       // [1024]  (sort phase)
    int* ncur = (int*)(uu + 4096);              // [1024]
    int* stmp = (int*)(uu + 8192);              // [512]

    const int b = blockIdx.x, t = threadIdx.x;
    const int s0 = bbase[b], s1 = bbase[b + 1];
    const int cntb = s1 - s0;
    const int cstage = min(cntb, MAXBUCK);

    for (int i = t; i < 1024; i += 512) cnt[i] = 0;
    __syncthreads();

    // stage + 1024-bin histogram
    for (int i = t; i < cstage; i += 512) {
        int2 p = payload[s0 + i];
        pseg[i] = p;
        atomicAdd(&cnt[(p.x >> 17) & 1023], 1);
    }
    __syncthreads();

    // exclusive scan of 1024 bins (512 thr x 2 elems)
    {
        int v0 = cnt[2 * t], v1 = cnt[2 * t + 1];
        int s = v0 + v1;
        stmp[t] = s;
        __syncthreads();
        for (int off = 1; off < 512; off <<= 1) {
            int x = (t >= off) ? stmp[t - off] : 0;
            __syncthreads();
            stmp[t] += x;
            __syncthreads();
        }
        int excl = stmp[t] - s;
        nbase[2 * t]     = excl;
        nbase[2 * t + 1] = excl + v0;
        ncur[2 * t]      = excl;
        ncur[2 * t + 1]  = excl + v0;
        if (t == 0) nbase[1024] = cstage;
    }
    __syncthreads();

    // scatter permutation indices (key-sorted order)
    for (int i = t; i < cstage; i += 512) {
        int key = (pseg[i].x >> 17) & 1023;
        int pos = atomicAdd(&ncur[key], 1);
        sidx[pos] = (unsigned short)i;
    }
    __syncthreads();   // sort done; uu region is now free for P

    const int lane = t & 63, w = t >> 6;
    const int lr = lane & 15, lg = lane >> 4;
    const int gg = t >> 3, q = t & 7;
    const int n0g = b << BSHIFT;
    const short* Wts = (const short*)Wt;

    f32x4 c0 = {0.f, 0.f, 0.f, 0.f};
    f32x4 c1 = {0.f, 0.f, 0.f, 0.f};
    f32x4 c2 = {0.f, 0.f, 0.f, 0.f};
    f32x4 c3 = {0.f, 0.f, 0.f, 0.f};

    for (int r = 0; r < NUM_RELS; ++r) {
        // --- gather phase: P_r rows in registers, write bf16 to LDS ---
        #pragma unroll
        for (int rr = 0; rr < 2; ++rr) {
            int nodeid = gg + rr * 64;
            int key = (r << 7) | nodeid;
            int j0 = nbase[key], j1 = nbase[key + 1];
            float s0_ = 0.f, s1_ = 0.f, s2_ = 0.f, s3_ = 0.f;
            float s4_ = 0.f, s5_ = 0.f, s6_ = 0.f, s7_ = 0.f;
            int j = j0;
            for (; j + 1 < j1; j += 2) {
                int2 pa = pseg[sidx[j]];
                int2 pb = pseg[sidx[j + 1]];
                uint4 ua = *(const uint4*)(featb + (size_t)(pa.x & 0x1FFFF) * 64 + (q << 3));
                uint4 ub = *(const uint4*)(featb + (size_t)(pb.x & 0x1FFFF) * 64 + (q << 3));
                float na = __int_as_float(pa.y), nb_ = __int_as_float(pb.y);
                s0_ += bflo(ua.x) * na; s1_ += bfhi(ua.x) * na;
                s2_ += bflo(ua.y) * na; s3_ += bfhi(ua.y) * na;
                s4_ += bflo(ua.z) * na; s5_ += bfhi(ua.z) * na;
                s6_ += bflo(ua.w) * na; s7_ += bfhi(ua.w) * na;
                s0_ += bflo(ub.x) * nb_; s1_ += bfhi(ub.x) * nb_;
                s2_ += bflo(ub.y) * nb_; s3_ += bfhi(ub.y) * nb_;
                s4_ += bflo(ub.z) * nb_; s5_ += bfhi(ub.z) * nb_;
                s6_ += bflo(ub.w) * nb_; s7_ += bfhi(ub.w) * nb_;
            }
            if (j < j1) {
                int2 p = pseg[sidx[j]];
                uint4 u = *(const uint4*)(featb + (size_t)(p.x & 0x1FFFF) * 64 + (q << 3));
                float nv = __int_as_float(p.y);
                s0_ += bflo(u.x) * nv; s1_ += bfhi(u.x) * nv;
                s2_ += bflo(u.y) * nv; s3_ += bfhi(u.y) * nv;
                s4_ += bflo(u.z) * nv; s5_ += bfhi(u.z) * nv;
                s6_ += bflo(u.w) * nv; s7_ += bfhi(u.w) * nv;
            }
            ushort8 pw;
            pw[0] = f2bf(s0_); pw[1] = f2bf(s1_); pw[2] = f2bf(s2_); pw[3] = f2bf(s3_);
            pw[4] = f2bf(s4_); pw[5] = f2bf(s5_); pw[6] = f2bf(s6_); pw[7] = f2bf(s7_);
            *(ushort8*)&P[nodeid * 72 + (q << 3)] = pw;
        }
        __syncthreads();

        // --- MFMA phase: C += P @ Wt[r]; wave w owns rows 16w..16w+15 ---
        short8 a0 = *(const short8*)&P[(16 * w + lr) * 72 + lg * 8];
        short8 a1 = *(const short8*)&P[(16 * w + lr) * 72 + 32 + lg * 8];
        {
            short8 b0, b1;
            b0 = *(const short8*)(Wts + ((size_t)r * 64 + 0 * 16 + lr) * 64 + lg * 8);
            b1 = *(const short8*)(Wts + ((size_t)r * 64 + 0 * 16 + lr) * 64 + 32 + lg * 8);
            c0 = __builtin_amdgcn_mfma_f32_16x16x32_bf16(a0, b0, c0, 0, 0, 0);
            c0 = __builtin_amdgcn_mfma_f32_16x16x32_bf16(a1, b1, c0, 0, 0, 0);
            b0 = *(const short8*)(Wts + ((size_t)r * 64 + 1 * 16 + lr) * 64 + lg * 8);
            b1 = *(const short8*)(Wts + ((size_t)r * 64 + 1 * 16 + lr) * 64 + 32 + lg * 8);
            c1 = __builtin_amdgcn_mfma_f32_16x16x32_bf16(a0, b0, c1, 0, 0, 0);
            c1 = __builtin_amdgcn_mfma_f32_16x16x32_bf16(a1, b1, c1, 0, 0, 0);
            b0 = *(const short8*)(Wts + ((size_t)r * 64 + 2 * 16 + lr) * 64 + lg * 8);
            b1 = *(const short8*)(Wts + ((size_t)r * 64 + 2 * 16 + lr) * 64 + 32 + lg * 8);
            c2 = __builtin_amdgcn_mfma_f32_16x16x32_bf16(a0, b0, c2, 0, 0, 0);
            c2 = __builtin_amdgcn_mfma_f32_16x16x32_bf16(a1, b1, c2, 0, 0, 0);
            b0 = *(const short8*)(Wts + ((size_t)r * 64 + 3 * 16 + lr) * 64 + lg * 8);
            b1 = *(const short8*)(Wts + ((size_t)r * 64 + 3 * 16 + lr) * 64 + 32 + lg * 8);
            c3 = __builtin_amdgcn_mfma_f32_16x16x32_bf16(a0, b0, c3, 0, 0, 0);
            c3 = __builtin_amdgcn_mfma_f32_16x16x32_bf16(a1, b1, c3, 0, 0, 0);
        }
        __syncthreads();   // P consumed before next pass overwrites
    }

    // store: C/D layout (m89/round-7-verified): reg j -> row=lg*4+j, col=nt*16+lr
    #pragma unroll
    for (int j = 0; j < 4; ++j) {
        int row = n0g + 16 * w + lg * 4 + j;
        if (row < N_NODES) {
            float* op = out + (size_t)row * OUT_FEAT;
            op[0 * 16 + lr] = c0[j];
            op[1 * 16 + lr] = c1[j];
            op[2 * 16 + lr] = c2[j];
            op[3 * 16 + lr] = c3[j];
        }
    }

    // overflow fallback (cntb > MAXBUCK): ~20-sigma margin, never taken for
    // this input; exact f32 per-edge matvec with atomics.
    if (cntb > MAXBUCK) {
        __syncthreads();   // all row stores of this block complete first
        for (int i = MAXBUCK + t; i < cntb; i += 512) {
            int2 p = payload[s0 + i];
            int srcn = p.x & 0x1FFFF;
            int rel  = (p.x >> 24) & 7;
            int n    = n0g + ((p.x >> 17) & 127);
            float nv = __int_as_float(p.y);
            if (n < N_NODES) {
                for (int c = 0; c < OUT_FEAT; ++c) {
                    float s = 0.f;
                    for (int i2 = 0; i2 < IN_FEAT; ++i2)
                        s += featf[(size_t)srcn * 64 + i2] * Worig[((size_t)rel * 64 + i2) * 64 + c];
                    atomicAdd(&out[(size_t)n * 64 + c], s * nv);
                }
            }
        }
    }
}

// ---------------------------------------------------------------------------
// Fallback (ws too small): direct per-edge matvec + atomic scatter.
// ---------------------------------------------------------------------------
__global__ __launch_bounds__(256) void k_direct(const float* __restrict__ feat,
                                                const float* __restrict__ W,
                                                const float* __restrict__ norm,
                                                const int* __restrict__ etypes,
                                                const int* __restrict__ src,
                                                const int* __restrict__ dst,
                                                float* __restrict__ out) {
    int gid = blockIdx.x * 256 + threadIdx.x;
    int e = gid >> 4;
    int q = gid & 15;
    if (e >= N_EDGES) return;
    float nv = norm[e];
    const float* fs = feat + (size_t)src[e] * IN_FEAT;
    const float* wp = W + (size_t)etypes[e] * 4096 + q * 4;
    float ax = 0.f, ay = 0.f, az = 0.f, aw = 0.f;
    #pragma unroll 8
    for (int i = 0; i < IN_FEAT; ++i) {
        float f = fs[i];
        float4 w = *(const float4*)(wp + i * OUT_FEAT);
        ax += f * w.x; ay += f * w.y; az += f * w.z; aw += f * w.w;
    }
    float* op = out + (size_t)dst[e] * OUT_FEAT + q * 4;
    atomicAdd(op + 0, ax * nv);
    atomicAdd(op + 1, ay * nv);
    atomicAdd(op + 2, az * nv);
    atomicAdd(op + 3, aw * nv);
}

extern "C" void kernel_launch(void* const* d_in, const int* in_sizes, int n_in,
                              void* d_out, int out_size, void* d_ws, size_t ws_size,
                              hipStream_t stream) {
    const float* feat   = (const float*)d_in[0];
    const float* norm   = (const float*)d_in[1];
    const float* W      = (const float*)d_in[2];
    const int*   etypes = (const int*)d_in[3];
    const int*   src    = (const int*)d_in[4];
    const int*   dst    = (const int*)d_in[5];
    float* out = (float*)d_out;

    const int nscat = (N_EDGES * 16) / 256;    // 100000 (fallback)

    // ws layout, 256B-aligned pieces  (~28 MB total)
    const size_t sz_featb = (size_t)N_NODES * IN_FEAT * 2;                      // 12.8 MB
    const size_t sz_wt    = (size_t)NUM_RELS * 64 * 64 * 2;                     // 64 KB
    const size_t sz_cnt   = (((size_t)NCHUNK * NB * 4) + 255) & ~(size_t)255;   // ~1.22 MB
    const size_t sz_poff  = (((size_t)NB * PSTR * 4) + 255) & ~(size_t)255;     // ~1.23 MB
    const size_t sz_btot  = 3328;
    const size_t sz_bbase = 3328;
    const size_t sz_pay   = (size_t)N_EDGES * 8;                                 // 12.8 MB

    char* p = (char*)d_ws;
    unsigned short* featb = (unsigned short*)p;  p += sz_featb;
    unsigned short* wt    = (unsigned short*)p;  p += sz_wt;
    int*  cnt_kb  = (int*)p;                     p += sz_cnt;
    int*  poff    = (int*)p;                     p += sz_poff;
    int*  btot    = (int*)p;                     p += sz_btot;
    int*  bbase   = (int*)p;                     p += sz_bbase;
    int2* payload = (int2*)p;                    p += sz_pay;
    const size_t need = (size_t)(p - (char*)d_ws);   // ~28.1 MB

    if (ws_size >= need) {
        k_prep       <<<NUM_RELS, 256, 0, stream>>>(W, wt);
        k_featb      <<<(N_NODES * 8 + 255) / 256, 256, 0, stream>>>(feat, featb);
        k_bhist      <<<NCHUNK, 256, 0, stream>>>(dst, cnt_kb);
        k_scan_bucket<<<NB,     256, 0, stream>>>(cnt_kb, poff, btot);
        k_scan_tot   <<<1,      256, 0, stream>>>(btot, bbase);
        k_bin        <<<NCHUNK, 256, 0, stream>>>(etypes, src, dst, norm, poff, bbase, payload);
        k_agg        <<<NB,     512, 0, stream>>>(featb, wt, W, feat, payload, bbase, out);
    } else {
        hipMemsetAsync(d_out, 0, (size_t)out_size * sizeof(float), stream);
        k_direct<<<nscat, 256, 0, stream>>>(feat, W, norm, etypes, src, dst, out);
    }
}

// Round 9
// 112.036 us; speedup vs baseline: 1.4479x; 1.4479x over previous
//
#include <hip/hip_runtime.h>
#include <hip/hip_bf16.h>

#define N_NODES 100000
#define N_EDGES 1600000
#define IN_FEAT 64
#define OUT_FEAT 64
#define NUM_RELS 8

#define BSHIFT 7
#define BSZ 128                                   // nodes per bucket
#define NB ((N_NODES + BSZ - 1) / BSZ)            // 782 buckets
#define CHUNK 4096
#define NCHUNK ((N_EDGES + CHUNK - 1) / CHUNK)    // 391 edge chunks
#define PSTR 392                                  // poff row stride
#define MAXBUCK 2944                              // bucket LDS cap (mean 2046, ~20 sigma)

typedef __attribute__((ext_vector_type(8))) short short8;
typedef __attribute__((ext_vector_type(8))) unsigned short ushort8;
typedef __attribute__((ext_vector_type(4))) float f32x4;

// bf16 helpers
static __device__ __forceinline__ unsigned short f2bf(float x) {
    unsigned u = __float_as_uint(x);
    unsigned r = (u + 0x7FFFu + ((u >> 16) & 1u)) >> 16;
    return (unsigned short)r;
}
static __device__ __forceinline__ float bf2f(unsigned short h) {
    return __uint_as_float(((unsigned)h) << 16);
}
static __device__ __forceinline__ float bflo(unsigned v) { return __uint_as_float(v << 16); }
static __device__ __forceinline__ float bfhi(unsigned v) { return __uint_as_float(v & 0xFFFF0000u); }

// ---------------------------------------------------------------------------
// K0: one-time W transpose+cast: Wt[r][o][i] (bf16) = W[r][i][o]. 64KB.
// ---------------------------------------------------------------------------
__global__ __launch_bounds__(256) void k_prep(const float* __restrict__ W,
                                              unsigned short* __restrict__ Wt) {
    __shared__ float Wl[64 * 64];   // [i][o]
    const int r = blockIdx.x, t = threadIdx.x;
    #pragma unroll
    for (int it = 0; it < 16; ++it) {
        int idx = it * 256 + t;
        Wl[idx] = W[(size_t)r * 4096 + idx];
    }
    __syncthreads();
    const int o = t >> 2, iq = t & 3;           // 16 i-values per thread
    unsigned short tmp[16];
    #pragma unroll
    for (int k = 0; k < 16; ++k) tmp[k] = f2bf(Wl[(iq * 16 + k) * 64 + o]);
    ushort8* dst = (ushort8*)(Wt + ((size_t)r * 64 + o) * 64 + iq * 16);
    dst[0] = *(ushort8*)&tmp[0];
    dst[1] = *(ushort8*)&tmp[8];
}

// ---------------------------------------------------------------------------
// K1 (MFMA): tr[r][n][o] (bf16) = sum_i feat[n][i] * W[r][i][o]
// (round-7 verified: 4 waves/block, 2 a-frags + 8 b-frags + 8 MFMAs per rel;
// C/D layout m89-verified: reg j -> row=(l>>4)*4+j, col=l&15.)
// ---------------------------------------------------------------------------
__global__ __launch_bounds__(256) void k_transform(const float* __restrict__ feat,
                                                   const unsigned short* __restrict__ Wt,
                                                   unsigned short* __restrict__ trb) {
    __shared__ unsigned short Ft[64 * 72];    // [row][k], pad 72
    __shared__ unsigned short Wtl[64 * 72];   // [col][k], pad 72
    const int tid = threadIdx.x;
    const int n0b = blockIdx.x * 64;
    const int lane = tid & 63, w = tid >> 6;
    const int lr = lane & 15, lg = lane >> 4;   // frag row/col, k-group

    // stage feat tile as bf16 (coalesced float4 reads, ushort4 LDS writes)
    #pragma unroll
    for (int it = 0; it < 4; ++it) {
        int m = it * 256 + tid;
        int row = m >> 4, c4 = m & 15;
        int gn = n0b + row;
        float4 v = make_float4(0.f, 0.f, 0.f, 0.f);
        if (gn < N_NODES) v = *(const float4*)(feat + (size_t)gn * IN_FEAT + c4 * 4);
        ushort4 sv;
        sv.x = f2bf(v.x); sv.y = f2bf(v.y); sv.z = f2bf(v.z); sv.w = f2bf(v.w);
        *(ushort4*)&Ft[row * 72 + c4 * 4] = sv;
    }

    for (int rel = 0; rel < NUM_RELS; ++rel) {
        __syncthreads();   // previous rel's Wtl reads done (also fences Ft stage on rel 0)
        #pragma unroll
        for (int it = 0; it < 2; ++it) {
            int m = it * 256 + tid;            // m in [0,512): 8 ushorts each
            int row = m >> 3, kq = m & 7;
            *(ushort8*)&Wtl[row * 72 + kq * 8] =
                *(const ushort8*)(Wt + (size_t)rel * 4096 + m * 8);
        }
        __syncthreads();

        // a-frags: row = 16w + lr, k = 32*ks + 8*lg
        short8 a0 = *(const short8*)&Ft[(16 * w + lr) * 72 + lg * 8];
        short8 a1 = *(const short8*)&Ft[(16 * w + lr) * 72 + 32 + lg * 8];

        #pragma unroll
        for (int nt = 0; nt < 4; ++nt) {
            short8 b0 = *(const short8*)&Wtl[(nt * 16 + lr) * 72 + lg * 8];
            short8 b1 = *(const short8*)&Wtl[(nt * 16 + lr) * 72 + 32 + lg * 8];
            f32x4 acc = {0.f, 0.f, 0.f, 0.f};
            acc = __builtin_amdgcn_mfma_f32_16x16x32_bf16(a0, b0, acc, 0, 0, 0);
            acc = __builtin_amdgcn_mfma_f32_16x16x32_bf16(a1, b1, acc, 0, 0, 0);
            #pragma unroll
            for (int j = 0; j < 4; ++j) {
                int row = n0b + 16 * w + lg * 4 + j;
                if (row < N_NODES)
                    trb[((size_t)rel * N_NODES + row) * OUT_FEAT + nt * 16 + lr] = f2bf(acc[j]);
            }
        }
    }
}

// ---------------------------------------------------------------------------
// Exclusive block scan over arr[0..1023] (LDS), 256 threads. Returns total.
// ---------------------------------------------------------------------------
__device__ __forceinline__ int block_scan1024(int* arr, int* tmp) {
    const int t = threadIdx.x;
    const int i0 = t * 4;
    int v0 = arr[i0], v1 = arr[i0 + 1], v2 = arr[i0 + 2], v3 = arr[i0 + 3];
    int s = v0 + v1 + v2 + v3;
    tmp[t] = s;
    __syncthreads();
    for (int off = 1; off < 256; off <<= 1) {
        int x = (t >= off) ? tmp[t - off] : 0;
        __syncthreads();
        tmp[t] += x;
        __syncthreads();
    }
    int excl = tmp[t] - s;
    int total = tmp[255];
    arr[i0]     = excl;
    arr[i0 + 1] = excl + v0;
    arr[i0 + 2] = excl + v0 + v1;
    arr[i0 + 3] = excl + v0 + v1 + v2;
    __syncthreads();
    return total;
}

// ---------------------------------------------------------------------------
// S1: per-chunk bucket histogram. cnt_kb[k][b] (coalesced writes).
// ---------------------------------------------------------------------------
__global__ __launch_bounds__(256) void k_bhist(const int* __restrict__ dst,
                                               int* __restrict__ cnt_kb) {
    __shared__ int h[NB];
    const int k = blockIdx.x, t = threadIdx.x;
    for (int i = t; i < NB; i += 256) h[i] = 0;
    __syncthreads();
    const int e0 = k * CHUNK;
    #pragma unroll
    for (int i = 0; i < 16; ++i) {
        int e = e0 + t + i * 256;
        if (e < N_EDGES) atomicAdd(&h[dst[e] >> BSHIFT], 1);
    }
    __syncthreads();
    for (int i = t; i < NB; i += 256) cnt_kb[(size_t)k * NB + i] = h[i];
}

// ---------------------------------------------------------------------------
// S2a: per-bucket prefix over chunks: poff[b][k]; bucket totals -> btot.
// ---------------------------------------------------------------------------
__global__ __launch_bounds__(256) void k_scan_bucket(const int* __restrict__ cnt_kb,
                                                     int* __restrict__ poff,
                                                     int* __restrict__ btot) {
    __shared__ int arr[1024];
    __shared__ int tmp[256];
    const int b = blockIdx.x, t = threadIdx.x;
    for (int i = t; i < 1024; i += 256)
        arr[i] = (i < NCHUNK) ? cnt_kb[(size_t)i * NB + b] : 0;
    __syncthreads();
    int total = block_scan1024(arr, tmp);
    for (int i = t; i < NCHUNK; i += 256) poff[(size_t)b * PSTR + i] = arr[i];
    if (t == 0) btot[b] = total;
}

// ---------------------------------------------------------------------------
// S2b: scan bucket totals -> bbase[0..NB], bbase[NB]=E.
// ---------------------------------------------------------------------------
__global__ __launch_bounds__(256) void k_scan_tot(const int* __restrict__ btot,
                                                  int* __restrict__ bbase) {
    __shared__ int arr[1024];
    __shared__ int tmp[256];
    const int t = threadIdx.x;
    for (int i = t; i < 1024; i += 256) arr[i] = (i < NB) ? btot[i] : 0;
    __syncthreads();
    block_scan1024(arr, tmp);
    for (int i = t; i < NB; i += 256) bbase[i] = arr[i];
    if (t == 0) bbase[NB] = N_EDGES;
}

// ---------------------------------------------------------------------------
// S3: bin edges into bucket-sorted payload with EXACT positions (line-dense
// writes). payload = { rowid | ldst<<20 , norm } (rowid = rel*N+src < 2^20).
// ---------------------------------------------------------------------------
__global__ __launch_bounds__(256) void k_bin(const int* __restrict__ etypes,
                                             const int* __restrict__ src,
                                             const int* __restrict__ dst,
                                             const float* __restrict__ norm,
                                             const int* __restrict__ poff,
                                             const int* __restrict__ bbase,
                                             int2* __restrict__ payload) {
    __shared__ int hist[1024];
    __shared__ int tmp[256];
    __shared__ int lcur[NB];
    __shared__ int goff[NB];
    __shared__ int2 ordered[CHUNK];
    __shared__ unsigned short bkt_of[CHUNK];
    const int k = blockIdx.x, t = threadIdx.x;
    const int e0 = k * CHUNK;
    const int cnt = min(CHUNK, N_EDGES - e0);

    for (int i = t; i < 1024; i += 256) hist[i] = 0;
    __syncthreads();
    #pragma unroll
    for (int i = 0; i < 16; ++i) {
        int e = e0 + t + i * 256;
        if (e < N_EDGES) atomicAdd(&hist[dst[e] >> BSHIFT], 1);
    }
    __syncthreads();
    block_scan1024(hist, tmp);           // hist -> local exclusive base
    for (int i = t; i < NB; i += 256) {
        int lb = hist[i];
        lcur[i] = lb;
        goff[i] = bbase[i] + poff[(size_t)i * PSTR + k] - lb;
    }
    __syncthreads();
    #pragma unroll
    for (int i = 0; i < 16; ++i) {
        int e = e0 + t + i * 256;
        if (e < N_EDGES) {
            int d = dst[e];
            int b = d >> BSHIFT;
            int pos = atomicAdd(&lcur[b], 1);
            int rowid = etypes[e] * N_NODES + src[e];
            ordered[pos] = make_int2(rowid | ((d & (BSZ - 1)) << 20), __float_as_int(norm[e]));
            bkt_of[pos] = (unsigned short)b;
        }
    }
    __syncthreads();
    for (int j = t; j < cnt; j += 256) {
        int b = bkt_of[j];
        payload[goff[b] + j] = ordered[j];   // consecutive j -> consecutive g within a run
    }
}

// ---------------------------------------------------------------------------
// S4: block (512 thr) per bucket, atomic-free register accumulation.
// Stage bucket payload in LDS, counting-sort by node, then 64 8-lane groups
// each own 2 nodes: gather bf16 trb rows (uint4/lane), accumulate in 8 f32
// regs, one direct row store per node (zeros for degree-0).
// ROUND-9 EXPERIMENT: 4-deep gather unroll (was 2) — diagnostic for
// latency-bound vs DRAM-random-line-wall on the 103MB unique-row fetch.
// ---------------------------------------------------------------------------
__global__ __launch_bounds__(512) void k_agg(const unsigned short* __restrict__ trb,
                                             const int2* __restrict__ payload,
                                             const int* __restrict__ bbase,
                                             float* __restrict__ out) {
    __shared__ int2 pseg[MAXBUCK];            // 23,552 B
    __shared__ unsigned short sidx[MAXBUCK];  //  5,888 B
    __shared__ int cnt128[BSZ];
    __shared__ int scan_tmp[BSZ];
    __shared__ int ncur[BSZ];
    __shared__ int nbase[BSZ + 1];
    const int b = blockIdx.x, t = threadIdx.x;

    const int s0 = bbase[b], s1 = bbase[b + 1];
    const int cntb = s1 - s0;
    const int cstage = min(cntb, MAXBUCK);

    if (t < BSZ) cnt128[t] = 0;
    __syncthreads();

    for (int i = t; i < cstage; i += 512) {
        int2 p = payload[s0 + i];
        pseg[i] = p;
        atomicAdd(&cnt128[(p.x >> 20) & 127], 1);
    }
    __syncthreads();

    if (t < BSZ) scan_tmp[t] = cnt128[t];
    __syncthreads();
    for (int off = 1; off < BSZ; off <<= 1) {
        int x = 0;
        if (t < BSZ && t >= off) x = scan_tmp[t - off];
        __syncthreads();
        if (t < BSZ) scan_tmp[t] += x;
        __syncthreads();
    }
    if (t < BSZ) {
        int inc = scan_tmp[t];
        int exc = inc - cnt128[t];
        nbase[t] = exc;
        ncur[t] = exc;
        if (t == BSZ - 1) nbase[BSZ] = inc;
    }
    __syncthreads();

    for (int i = t; i < cstage; i += 512) {
        int ld = (pseg[i].x >> 20) & 127;
        int pos = atomicAdd(&ncur[ld], 1);
        sidx[pos] = (unsigned short)i;
    }
    __syncthreads();

    const int gg = t >> 3;          // group id 0..63
    const int q  = t & 7;           // lane within group
    const int n0g = b << BSHIFT;

    #pragma unroll
    for (int rr = 0; rr < 2; ++rr) {
        int r = gg + rr * 64;
        int j0 = nbase[r], j1 = nbase[r + 1];
        float a0 = 0.f, a1 = 0.f, a2 = 0.f, a3 = 0.f;
        float a4 = 0.f, a5 = 0.f, a6 = 0.f, a7 = 0.f;
        int j = j0;
        for (; j + 3 < j1; j += 4) {      // 4 independent row-fetches in flight
            int2 p0 = pseg[sidx[j]];
            int2 p1 = pseg[sidx[j + 1]];
            int2 p2 = pseg[sidx[j + 2]];
            int2 p3 = pseg[sidx[j + 3]];
            uint4 u0 = *(const uint4*)(trb + (size_t)(p0.x & 0xFFFFF) * OUT_FEAT + (q << 3));
            uint4 u1 = *(const uint4*)(trb + (size_t)(p1.x & 0xFFFFF) * OUT_FEAT + (q << 3));
            uint4 u2 = *(const uint4*)(trb + (size_t)(p2.x & 0xFFFFF) * OUT_FEAT + (q << 3));
            uint4 u3 = *(const uint4*)(trb + (size_t)(p3.x & 0xFFFFF) * OUT_FEAT + (q << 3));
            float n0 = __int_as_float(p0.y), n1 = __int_as_float(p1.y);
            float n2 = __int_as_float(p2.y), n3 = __int_as_float(p3.y);
            a0 += bflo(u0.x) * n0; a1 += bfhi(u0.x) * n0;
            a2 += bflo(u0.y) * n0; a3 += bfhi(u0.y) * n0;
            a4 += bflo(u0.z) * n0; a5 += bfhi(u0.z) * n0;
            a6 += bflo(u0.w) * n0; a7 += bfhi(u0.w) * n0;
            a0 += bflo(u1.x) * n1; a1 += bfhi(u1.x) * n1;
            a2 += bflo(u1.y) * n1; a3 += bfhi(u1.y) * n1;
            a4 += bflo(u1.z) * n1; a5 += bfhi(u1.z) * n1;
            a6 += bflo(u1.w) * n1; a7 += bfhi(u1.w) * n1;
            a0 += bflo(u2.x) * n2; a1 += bfhi(u2.x) * n2;
            a2 += bflo(u2.y) * n2; a3 += bfhi(u2.y) * n2;
            a4 += bflo(u2.z) * n2; a5 += bfhi(u2.z) * n2;
            a6 += bflo(u2.w) * n2; a7 += bfhi(u2.w) * n2;
            a0 += bflo(u3.x) * n3; a1 += bfhi(u3.x) * n3;
            a2 += bflo(u3.y) * n3; a3 += bfhi(u3.y) * n3;
            a4 += bflo(u3.z) * n3; a5 += bfhi(u3.z) * n3;
            a6 += bflo(u3.w) * n3; a7 += bfhi(u3.w) * n3;
        }
        for (; j < j1; ++j) {
            int2 p = pseg[sidx[j]];
            uint4 u = *(const uint4*)(trb + (size_t)(p.x & 0xFFFFF) * OUT_FEAT + (q << 3));
            float nv = __int_as_float(p.y);
            a0 += bflo(u.x) * nv; a1 += bfhi(u.x) * nv;
            a2 += bflo(u.y) * nv; a3 += bfhi(u.y) * nv;
            a4 += bflo(u.z) * nv; a5 += bfhi(u.z) * nv;
            a6 += bflo(u.w) * nv; a7 += bfhi(u.w) * nv;
        }
        int n = n0g + (gg + rr * 64);
        if (n < N_NODES) {
            float* op = out + (size_t)n * OUT_FEAT + (q << 3);
            *(float4*)op       = make_float4(a0, a1, a2, a3);
            *(float4*)(op + 4) = make_float4(a4, a5, a6, a7);
        }
    }

    if (cntb > MAXBUCK) {   // ~20-sigma safety path, never taken for this input
        __syncthreads();
        for (int i = MAXBUCK + t; i < cntb; i += 512) {
            int2 p = payload[s0 + i];
            int row = p.x & 0xFFFFF;
            int n = n0g + ((p.x >> 20) & 127);
            float nv = __int_as_float(p.y);
            if (n < N_NODES)
                for (int c = 0; c < OUT_FEAT; ++c)
                    atomicAdd(&out[(size_t)n * OUT_FEAT + c],
                              bf2f(trb[(size_t)row * OUT_FEAT + c]) * nv);
        }
    }
}

// ---------------------------------------------------------------------------
// Fallbacks for small ws.
// ---------------------------------------------------------------------------
__global__ __launch_bounds__(256) void k_scatter(const unsigned short* __restrict__ trb,
                                                 const float* __restrict__ norm,
                                                 const int* __restrict__ etypes,
                                                 const int* __restrict__ src,
                                                 const int* __restrict__ dst,
                                                 float* __restrict__ out) {
    int gid = blockIdx.x * 256 + threadIdx.x;
    int e = gid >> 4;
    int q = gid & 15;
    if (e >= N_EDGES) return;
    float nv = norm[e];
    const unsigned short* rp = trb + ((size_t)etypes[e] * N_NODES + src[e]) * OUT_FEAT + q * 4;
    ushort4 u = *(const ushort4*)rp;
    float* op = out + (size_t)dst[e] * OUT_FEAT + q * 4;
    atomicAdd(op + 0, bf2f(u.x) * nv);
    atomicAdd(op + 1, bf2f(u.y) * nv);
    atomicAdd(op + 2, bf2f(u.z) * nv);
    atomicAdd(op + 3, bf2f(u.w) * nv);
}

__global__ __launch_bounds__(256) void k_direct(const float* __restrict__ feat,
                                                const float* __restrict__ W,
                                                const float* __restrict__ norm,
                                                const int* __restrict__ etypes,
                                                const int* __restrict__ src,
                                                const int* __restrict__ dst,
                                                float* __restrict__ out) {
    int gid = blockIdx.x * 256 + threadIdx.x;
    int e = gid >> 4;
    int q = gid & 15;
    if (e >= N_EDGES) return;
    float nv = norm[e];
    const float* fs = feat + (size_t)src[e] * IN_FEAT;
    const float* wp = W + (size_t)etypes[e] * 4096 + q * 4;
    float ax = 0.f, ay = 0.f, az = 0.f, aw = 0.f;
    #pragma unroll 8
    for (int i = 0; i < IN_FEAT; ++i) {
        float f = fs[i];
        float4 w = *(const float4*)(wp + i * OUT_FEAT);
        ax += f * w.x; ay += f * w.y; az += f * w.z; aw += f * w.w;
    }
    float* op = out + (size_t)dst[e] * OUT_FEAT + q * 4;
    atomicAdd(op + 0, ax * nv);
    atomicAdd(op + 1, ay * nv);
    atomicAdd(op + 2, az * nv);
    atomicAdd(op + 3, aw * nv);
}

extern "C" void kernel_launch(void* const* d_in, const int* in_sizes, int n_in,
                              void* d_out, int out_size, void* d_ws, size_t ws_size,
                              hipStream_t stream) {
    const float* feat   = (const float*)d_in[0];
    const float* norm   = (const float*)d_in[1];
    const float* W      = (const float*)d_in[2];
    const int*   etypes = (const int*)d_in[3];
    const int*   src    = (const int*)d_in[4];
    const int*   dst    = (const int*)d_in[5];
    float* out = (float*)d_out;

    const int ntiles = (N_NODES + 63) / 64;    // 1563
    const int nscat  = (N_EDGES * 16) / 256;   // 100000

    // ws layout, 256B-aligned pieces
    const size_t sz_tr    = (size_t)NUM_RELS * N_NODES * OUT_FEAT * 2;          // 102,400,000
    const size_t sz_wt    = (size_t)NUM_RELS * 64 * 64 * 2;                     // 65,536
    const size_t sz_cnt   = (((size_t)NCHUNK * NB * 4) + 255) & ~(size_t)255;   // ~1.22 MB
    const size_t sz_poff  = (((size_t)NB * PSTR * 4) + 255) & ~(size_t)255;     // ~1.23 MB
    const size_t sz_btot  = 3328;
    const size_t sz_bbase = 3328;
    const size_t sz_pay   = (size_t)N_EDGES * 8;                                 // 12.8 MB

    char* p = (char*)d_ws;
    unsigned short* trb = (unsigned short*)p;  p += sz_tr;
    unsigned short* wt  = (unsigned short*)p;  p += sz_wt;
    int*  cnt_kb  = (int*)p;                   p += sz_cnt;
    int*  poff    = (int*)p;                   p += sz_poff;
    int*  btot    = (int*)p;                   p += sz_btot;
    int*  bbase   = (int*)p;                   p += sz_bbase;
    int2* payload = (int2*)p;                  p += sz_pay;
    const size_t need = (size_t)(p - (char*)d_ws);   // ~117.8 MB

    if (ws_size >= need) {
        k_prep       <<<NUM_RELS, 256, 0, stream>>>(W, wt);
        k_transform  <<<ntiles, 256, 0, stream>>>(feat, wt, trb);
        k_bhist      <<<NCHUNK, 256, 0, stream>>>(dst, cnt_kb);
        k_scan_bucket<<<NB,     256, 0, stream>>>(cnt_kb, poff, btot);
        k_scan_tot   <<<1,      256, 0, stream>>>(btot, bbase);
        k_bin        <<<NCHUNK, 256, 0, stream>>>(etypes, src, dst, norm, poff, bbase, payload);
        k_agg        <<<NB,     512, 0, stream>>>(trb, payload, bbase, out);
    } else if (ws_size >= sz_tr + sz_wt) {
        hipMemsetAsync(d_out, 0, (size_t)out_size * sizeof(float), stream);
        k_prep     <<<NUM_RELS, 256, 0, stream>>>(W, wt);
        k_transform<<<ntiles, 256, 0, stream>>>(feat, wt, trb);
        k_scatter  <<<nscat, 256, 0, stream>>>(trb, norm, etypes, src, dst, out);
    } else {
        hipMemsetAsync(d_out, 0, (size_t)out_size * sizeof(float), stream);
        k_direct<<<nscat, 256, 0, stream>>>(feat, W, norm, etypes, src, dst, out);
    }
}